// Round 10
// baseline (165.757 us; speedup 1.0000x reference)
//
#include <hip/hip_runtime.h>
#include <math.h>

typedef unsigned short bf16;
typedef unsigned long long u64;
typedef __attribute__((ext_vector_type(8))) short short8;
typedef __attribute__((ext_vector_type(4))) short s16x4;
typedef __attribute__((ext_vector_type(4))) float f32x4;

#define S_LEN 2048
#define NH    16
#define DH    64
#define DM    1024
#define BATCH 2

__device__ __forceinline__ bf16 f2bf(float f) {
    unsigned u = __float_as_uint(f);
    u += 0x7fffu + ((u >> 16) & 1u);          // RNE
    return (bf16)(u >> 16);
}

// pack two floats to packed bf16x2 (round-half-up; cheap)
__device__ __forceinline__ unsigned pack2(float a, float b) {
    unsigned ua = __float_as_uint(a) + 0x8000u;
    unsigned ub = __float_as_uint(b) + 0x8000u;
    return (ua >> 16) | (ub & 0xFFFF0000u);
}

__device__ __forceinline__ u64 pack4(f32x4 v) {
    return (u64)pack2(v[0], v[1]) | ((u64)pack2(v[2], v[3]) << 32);
}

__device__ __forceinline__ s16x4 pack4s(f32x4 v) {
    union { uint2 u; s16x4 s; } cv;
    cv.u = make_uint2(pack2(v[0], v[1]), pack2(v[2], v[3]));
    return cv.s;
}

__device__ __forceinline__ float fast_exp2(float x) {
#if __has_builtin(__builtin_amdgcn_exp2f)
    return __builtin_amdgcn_exp2f(x);
#else
    return exp2f(x);
#endif
}

// async global->LDS, 16B per lane.  dest = wave-uniform base + lane*16.
__device__ __forceinline__ void gload_lds16(const void* g, void* s) {
    __builtin_amdgcn_global_load_lds(
        (const __attribute__((address_space(1))) unsigned int*)g,
        (__attribute__((address_space(3))) unsigned int*)s, 16, 0, 0);
}

// -------------------------------------------------------------------------
// Convert fp32 -> bf16.  W_Q scale folded = 0.125*log2(e) (exp2-domain
// softmax).  WO transposed via LDS tiles (coalesced 128B store segments).
// -------------------------------------------------------------------------
#define QSCALE 0.18033688011112042f

__global__ __launch_bounds__(256) void convert_kernel(
    const float* __restrict__ X,  const float* __restrict__ WQ,
    const float* __restrict__ WK, const float* __restrict__ WV,
    const float* __restrict__ WO,
    bf16* __restrict__ Xb, bf16* __restrict__ WQb, bf16* __restrict__ WKb,
    bf16* __restrict__ WVb, bf16* __restrict__ WOt)
{
    __shared__ float T[64][65];
    const int blk = blockIdx.x;
    if (blk < 7168) {
        const int t = blk * 256 + threadIdx.x;
        if (t < 1048576) {                         // X
            float4 v = ((const float4*)X)[t];
            u64 pk = (u64)f2bf(v.x) | ((u64)f2bf(v.y) << 16)
                   | ((u64)f2bf(v.z) << 32) | ((u64)f2bf(v.w) << 48);
            *(u64*)(Xb + 4 * (size_t)t) = pk;
        } else if (t < 1310720) {                  // WQ (scaled)
            int i = t - 1048576;
            float4 v = ((const float4*)WQ)[i];
            u64 pk = (u64)f2bf(v.x * QSCALE) | ((u64)f2bf(v.y * QSCALE) << 16)
                   | ((u64)f2bf(v.z * QSCALE) << 32) | ((u64)f2bf(v.w * QSCALE) << 48);
            *(u64*)(WQb + 4 * (size_t)i) = pk;
        } else if (t < 1572864) {                  // WK
            int i = t - 1310720;
            float4 v = ((const float4*)WK)[i];
            u64 pk = (u64)f2bf(v.x) | ((u64)f2bf(v.y) << 16)
                   | ((u64)f2bf(v.z) << 32) | ((u64)f2bf(v.w) << 48);
            *(u64*)(WKb + 4 * (size_t)i) = pk;
        } else {                                   // WV
            int i = t - 1572864;
            float4 v = ((const float4*)WV)[i];
            u64 pk = (u64)f2bf(v.x) | ((u64)f2bf(v.y) << 16)
                   | ((u64)f2bf(v.z) << 32) | ((u64)f2bf(v.w) << 48);
            *(u64*)(WVb + 4 * (size_t)i) = pk;
        }
    } else {                                       // WO transpose tile 64x64
        const int tile = blk - 7168;               // 0..255
        const int he0 = (tile & 15) * 64, d0 = (tile >> 4) * 64;
        const int tid = threadIdx.x;
        const int row = tid >> 2, c0 = (tid & 3) * 16;
        #pragma unroll
        for (int u = 0; u < 4; ++u) {
            float4 v = *(const float4*)(WO + (size_t)(he0 + row) * DM + d0 + c0 + u * 4);
            T[row][c0 + u * 4 + 0] = v.x;
            T[row][c0 + u * 4 + 1] = v.y;
            T[row][c0 + u * 4 + 2] = v.z;
            T[row][c0 + u * 4 + 3] = v.w;
        }
        __syncthreads();
        bf16 tmp[16];
        #pragma unroll
        for (int j = 0; j < 16; ++j) tmp[j] = f2bf(T[c0 + j][row]);
        *(short8*)(WOt + (size_t)(d0 + row) * DM + he0 + c0)     = *(short8*)&tmp[0];
        *(short8*)(WOt + (size_t)(d0 + row) * DM + he0 + c0 + 8) = *(short8*)&tmp[8];
    }
}

// -------------------------------------------------------------------------
// Merged projections, double-buffered staging (64 KB LDS), one launch.
// XCD-affinity mapping: all 24 blocks sharing one X token-tile (8 Q he-tiles,
// 8 K he-tiles, 8 V he-tiles) get ids congruent mod 8, so round-robin
// dispatch pins them to one XCD -> X tile staged once into that L2.
// -------------------------------------------------------------------------
__global__ __launch_bounds__(256) void proj_kernel(
    const bf16* __restrict__ Xb, const bf16* __restrict__ WQb,
    const bf16* __restrict__ WKb, const bf16* __restrict__ WVb,
    bf16* __restrict__ qbuf, bf16* __restrict__ kbuf, bf16* __restrict__ vt)
{
    __shared__ char lds[65536];

    const int id = blockIdx.x;
    const int tid = threadIdx.x, wave = tid >> 6, lane = tid & 63;
    const int tx = lane & 15, quad = lane >> 4;
    const int wm = (wave >> 1) * 64, wn = (wave & 1) * 64;

    const int xcd = id & 7, slot = id >> 3;      // 96 slots
    const int tok = xcd + 8 * (slot / 24);       // token-tile 0..31
    const int within = slot % 24;

    int mode, am0, bn0, bb = 0;
    const bf16 *Aop, *Bop;
    if (within < 16) {
        mode = within >> 3;               // 0=Q, 1=K
        am0 = (within & 7) * 128;         // he rows (A)
        bn0 = tok * 128;                  // token rows (B)
        Aop = (mode ? WKb : WQb) + (size_t)am0 * DM;
        Bop = Xb + (size_t)bn0 * DM;
    } else {
        mode = 2;
        bn0 = (within - 16) * 128;        // he rows (B)
        bb  = tok >> 4;
        am0 = (tok & 15) * 128;           // s rows (A, within batch)
        Aop = Xb + ((size_t)bb * S_LEN + am0) * DM;
        Bop = WVb + (size_t)bn0 * DM;
    }

    f32x4 acc[4][4] = {};

    // prologue: stage k-slice 0 into buffer 0
    {
        char* As = lds;
        char* Bs = lds + 16384;
        #pragma unroll
        for (int r = 0; r < 4; ++r) {
            int slot2 = r * 256 + tid;
            int row = slot2 >> 3, g = slot2 & 7, gl = g ^ (row & 7);
            gload_lds16(Aop + (size_t)row * DM + gl * 8, As + r * 4096 + wave * 1024);
            gload_lds16(Bop + (size_t)row * DM + gl * 8, Bs + r * 4096 + wave * 1024);
        }
    }

    for (int kt = 0; kt < 16; ++kt) {
        char* As = lds + (kt & 1) * 32768;
        char* Bs = As + 16384;
        __syncthreads();                       // current buffer ready

        if (kt < 15) {                         // prefetch next k-slice
            char* An = lds + ((kt + 1) & 1) * 32768;
            char* Bn = An + 16384;
            const int k0 = (kt + 1) * 64;
            #pragma unroll
            for (int r = 0; r < 4; ++r) {
                int slot2 = r * 256 + tid;
                int row = slot2 >> 3, g = slot2 & 7, gl = g ^ (row & 7);
                gload_lds16(Aop + (size_t)row * DM + k0 + gl * 8,
                            An + r * 4096 + wave * 1024);
                gload_lds16(Bop + (size_t)row * DM + k0 + gl * 8,
                            Bn + r * 4096 + wave * 1024);
            }
        }

        #pragma unroll
        for (int ks = 0; ks < 2; ++ks) {
            const int swz = ((ks * 4 + quad) ^ (tx & 7)) * 16;
            short8 af[4], bfr[4];
            #pragma unroll
            for (int mt = 0; mt < 4; ++mt)
                af[mt] = *(const short8*)(As + (wm + mt * 16 + tx) * 128 + swz);
            #pragma unroll
            for (int nt = 0; nt < 4; ++nt)
                bfr[nt] = *(const short8*)(Bs + (wn + nt * 16 + tx) * 128 + swz);
            #pragma unroll
            for (int mt = 0; mt < 4; ++mt)
                #pragma unroll
                for (int nt = 0; nt < 4; ++nt)
                    acc[mt][nt] = __builtin_amdgcn_mfma_f32_16x16x32_bf16(
                        af[mt], bfr[nt], acc[mt][nt], 0, 0, 0);
        }
    }

    if (mode < 2) {
        bf16* outb = mode ? kbuf : qbuf;
        #pragma unroll
        for (int mt = 0; mt < 4; ++mt)
            #pragma unroll
            for (int nt = 0; nt < 4; ++nt) {
                int heG  = am0 + wm + mt * 16 + quad * 4;    // + r in reg
                int tokG = bn0 + wn + nt * 16 + tx;
                int b = tokG >> 11, s = tokG & 2047;
                int h = heG >> 6, e0 = heG & 63;
                *(u64*)(outb + ((size_t)(b * NH + h) * S_LEN + s) * DH + e0) =
                    pack4(acc[mt][nt]);
            }
    } else {
        #pragma unroll
        for (int mt = 0; mt < 4; ++mt)
            #pragma unroll
            for (int nt = 0; nt < 4; ++nt) {
                int sG  = am0 + wm + mt * 16 + quad * 4;     // + r in reg
                int heG = bn0 + wn + nt * 16 + tx;
                *(u64*)(vt + ((size_t)bb * DM + heG) * S_LEN + sG) =
                    pack4(acc[mt][nt]);
            }
    }
}

// -------------------------------------------------------------------------
// Flash attention.  Q-tile 64 (4 waves x 16 q), K-tile 64, dbuf K/V
// (32 KB LDS).  Grid 1024 = 4 blocks/CU fully resident; balanced mapping.
// S^T via 16x16x32 MFMA; fixed-base exp2 softmax; PV via chained 16x16x16
// MFMA straight from registers.  Causal diagonal block-uniform (kmax = qb).
// -------------------------------------------------------------------------
__global__ __launch_bounds__(256) void flash_kernel(
    const bf16* __restrict__ qbuf, const bf16* __restrict__ kbuf,
    const bf16* __restrict__ vtb, bf16* __restrict__ attn)
{
    __shared__ char lds[32768];

    const int i  = blockIdx.x;
    const int bh = i & 31;
    const int j  = i >> 5;
    const int qb = (i < 512) ? (31 - j) : (j - 16);  // heavy-first, paired
    const int tid = threadIdx.x, wave = tid >> 6, lane = tid & 63;
    const int tx = lane & 15, quad = lane >> 4;
    const int sw = tx & 7;

    const bf16* Qg = qbuf + (size_t)bh * S_LEN * DH + (size_t)qb * 64 * DH;
    const bf16* Kg = kbuf + (size_t)bh * S_LEN * DH;
    const bf16* Vg = vtb  + (size_t)bh * DH * S_LEN;

    // Q fragments straight from global: B-frag = 16B contiguous e per lane
    short8 bq[2];
    #pragma unroll
    for (int es = 0; es < 2; ++es)
        bq[es] = *(const short8*)(Qg + (size_t)(wave * 16 + tx) * DH +
                                  (es * 4 + quad) * 8);

    f32x4 oacc[4] = {};
    float l_part = 0.0f;

    const int kmax = qb;                       // block-uniform causal bound
    const int qg0  = qb * 64 + wave * 16 + tx;

    // stage k-tile 0 into buffer 0 (K: lds+0, V: lds+8192)
    #pragma unroll
    for (int r = 0; r < 2; ++r) {
        int slot = r * 256 + tid;
        int row = slot >> 3, g = slot & 7, gl = g ^ (row & 7);
        gload_lds16(Kg + (size_t)row * DH + gl * 8, lds + r * 4096 + wave * 1024);
        gload_lds16(Vg + (size_t)row * S_LEN + gl * 8,
                    lds + 8192 + r * 4096 + wave * 1024);
    }

    for (int kt64 = 0; kt64 <= kmax; ++kt64) {
        char* Kc = lds + (kt64 & 1) * 16384;
        char* Vc = Kc + 8192;
        __syncthreads();                       // current buffer ready

        if (kt64 < kmax) {                     // prefetch next tile
            char* Kn = lds + ((kt64 + 1) & 1) * 16384;
            char* Vn = Kn + 8192;
            #pragma unroll
            for (int r = 0; r < 2; ++r) {
                int slot = r * 256 + tid;
                int row = slot >> 3, g = slot & 7, gl = g ^ (row & 7);
                gload_lds16(Kg + ((size_t)(kt64 + 1) * 64 + row) * DH + gl * 8,
                            Kn + r * 4096 + wave * 1024);
                gload_lds16(Vg + (size_t)row * S_LEN + (kt64 + 1) * 64 + gl * 8,
                            Vn + r * 4096 + wave * 1024);
            }
        }

        // S^T = K * Q^T   (D[m=k][n=q])
        f32x4 st[4] = {};
        #pragma unroll
        for (int es = 0; es < 2; ++es) {
            #pragma unroll
            for (int kt = 0; kt < 4; ++kt) {
                short8 ak = *(const short8*)(Kc + (kt * 16 + tx) * 128 +
                                             (((es * 4 + quad) ^ sw) * 16));
                st[kt] = __builtin_amdgcn_mfma_f32_16x16x32_bf16(
                    ak, bq[es], st[kt], 0, 0, 0);
            }
        }

        if (kt64 == kmax) {                    // causal mask on diagonal tile
            #pragma unroll
            for (int kt = 0; kt < 4; ++kt)
                #pragma unroll
                for (int r = 0; r < 4; ++r)
                    if (kt64 * 64 + kt * 16 + quad * 4 + r > qg0)
                        st[kt][r] = -1e30f;
        }

        // fixed-base softmax: p = 2^s; pack P into 16x16x16 B-frags
        s16x4 pb[4];
        float rs = 0.0f;
        #pragma unroll
        for (int kt = 0; kt < 4; ++kt) {
            #pragma unroll
            for (int r = 0; r < 4; ++r) {
                float p = fast_exp2(st[kt][r]);
                st[kt][r] = p;
                rs += p;
            }
            pb[kt] = pack4s(st[kt]);
        }
        l_part += rs;

        // O^T += V^T * P, chained 16x16x16 MFMA (P from registers)
        #pragma unroll
        for (int kt = 0; kt < 4; ++kt) {
            #pragma unroll
            for (int et = 0; et < 4; ++et) {
                s16x4 av = *(const s16x4*)(Vc + (et * 16 + tx) * 128 +
                             (((kt * 2 + (quad >> 1)) ^ sw) * 16) + (quad & 1) * 8);
                oacc[et] = __builtin_amdgcn_mfma_f32_16x16x16bf16_1k(
                    av, pb[kt], oacc[et], 0, 0, 0);
            }
        }
    }

    // epilogue: reduce l across quads, divide, pack, un-transpose via LDS
    const int b = bh >> 4, h = bh & 15;
    char* Pw = lds + ((kmax & 1) ^ 1) * 16384 + wave * 2048;
    float l = l_part;
    l += __shfl_xor(l, 16);
    l += __shfl_xor(l, 32);
    float inv = 1.0f / l;
    #pragma unroll
    for (int et = 0; et < 4; ++et) {
        unsigned lo = pack2(oacc[et][0] * inv, oacc[et][1] * inv);
        unsigned hi = pack2(oacc[et][2] * inv, oacc[et][3] * inv);
        int eg = et * 2 + (quad >> 1);
        *(uint2*)(Pw + tx * 128 + ((eg ^ sw) * 16) + (quad & 1) * 8) =
            make_uint2(lo, hi);
    }
    asm volatile("s_waitcnt lgkmcnt(0)" ::: "memory");

    const int s = qb * 64 + wave * 16 + tx;
    bf16* op = attn + ((size_t)b * S_LEN + s) * DM + h * DH;
    #pragma unroll
    for (int c2 = 0; c2 < 2; ++c2) {
        int c = quad + c2 * 4;
        short8 v = *(const short8*)(Pw + tx * 128 + ((c ^ sw) * 16));
        *(short8*)(op + c * 8) = v;
    }
}

// -------------------------------------------------------------------------
// Output projection: out = attn(bf16) * WOt^T, fp32 out.  64x64 tiles,
// grid 1024 = 4 blocks/CU, dbuf 32 KB LDS, wave tile 16x64.
// -------------------------------------------------------------------------
__global__ __launch_bounds__(256) void out_proj_kernel(
    const bf16* __restrict__ A, const bf16* __restrict__ Bt,
    float* __restrict__ out)
{
    __shared__ char lds[32768];

    const int m0 = blockIdx.x * 64, n0 = blockIdx.y * 64;
    const int tid = threadIdx.x, wave = tid >> 6, lane = tid & 63;
    const int tx = lane & 15, quad = lane >> 4;
    const int wm = wave * 16;

    f32x4 acc[4] = {};

    // prologue: stage k-slice 0 into buffer 0 (A 8KB + B 8KB)
    {
        char* As = lds;
        char* Bs = lds + 8192;
        #pragma unroll
        for (int r = 0; r < 2; ++r) {
            int slot = r * 256 + tid;
            int row = slot >> 3, g = slot & 7, gl = g ^ (row & 7);
            gload_lds16(A + (size_t)(m0 + row) * DM + gl * 8,
                        As + r * 4096 + wave * 1024);
            gload_lds16(Bt + (size_t)(n0 + row) * DM + gl * 8,
                        Bs + r * 4096 + wave * 1024);
        }
    }

    for (int kt = 0; kt < 16; ++kt) {
        char* As = lds + (kt & 1) * 16384;
        char* Bs = As + 8192;
        __syncthreads();

        if (kt < 15) {
            char* An = lds + ((kt + 1) & 1) * 16384;
            char* Bn = An + 8192;
            const int k0 = (kt + 1) * 64;
            #pragma unroll
            for (int r = 0; r < 2; ++r) {
                int slot = r * 256 + tid;
                int row = slot >> 3, g = slot & 7, gl = g ^ (row & 7);
                gload_lds16(A + (size_t)(m0 + row) * DM + k0 + gl * 8,
                            An + r * 4096 + wave * 1024);
                gload_lds16(Bt + (size_t)(n0 + row) * DM + k0 + gl * 8,
                            Bn + r * 4096 + wave * 1024);
            }
        }

        #pragma unroll
        for (int ks = 0; ks < 2; ++ks) {
            const int swz = ((ks * 4 + quad) ^ (tx & 7)) * 16;
            short8 af = *(const short8*)(As + (wm + tx) * 128 + swz);
            short8 bfr[4];
            #pragma unroll
            for (int nt = 0; nt < 4; ++nt)
                bfr[nt] = *(const short8*)(Bs + (nt * 16 + tx) * 128 + swz);
            #pragma unroll
            for (int nt = 0; nt < 4; ++nt)
                acc[nt] = __builtin_amdgcn_mfma_f32_16x16x32_bf16(
                    af, bfr[nt], acc[nt], 0, 0, 0);
        }
    }

    #pragma unroll
    for (int nt = 0; nt < 4; ++nt)
        #pragma unroll
        for (int r = 0; r < 4; ++r) {
            int mG = m0 + wm + quad * 4 + r;
            int nG = n0 + nt * 16 + tx;
            out[(size_t)mG * DM + nG] = acc[nt][r];
        }
}

// -------------------------------------------------------------------------
extern "C" void kernel_launch(void* const* d_in, const int* in_sizes, int n_in,
                              void* d_out, int out_size, void* d_ws, size_t ws_size,
                              hipStream_t stream) {
    const float* X  = (const float*)d_in[0];
    const float* WQ = (const float*)d_in[1];
    const float* WK = (const float*)d_in[2];
    const float* WV = (const float*)d_in[3];
    const float* WO = (const float*)d_in[4];
    float* out = (float*)d_out;

    char* ws = (char*)d_ws;
    bf16* Xb   = (bf16*)(ws);                          // 8 MB
    bf16* WQb  = (bf16*)(ws + (8u  << 20));            // 2 MB
    bf16* WKb  = (bf16*)(ws + (10u << 20));            // 2 MB
    bf16* WVb  = (bf16*)(ws + (12u << 20));            // 2 MB
    bf16* WOt  = (bf16*)(ws + (14u << 20));            // 2 MB
    bf16* qbuf = (bf16*)(ws + (16u << 20));            // 8 MB
    bf16* kbuf = (bf16*)(ws + (24u << 20));            // 8 MB
    bf16* vt   = (bf16*)(ws + (32u << 20));            // 8 MB
    bf16* attn = (bf16*)(ws + (40u << 20));            // 8 MB

    convert_kernel<<<7424, 256, 0, stream>>>(X, WQ, WK, WV, WO,
                                             Xb, WQb, WKb, WVb, WOt);
    proj_kernel<<<768, 256, 0, stream>>>(Xb, WQb, WKb, WVb, qbuf, kbuf, vt);
    flash_kernel<<<1024, 256, 0, stream>>>(qbuf, kbuf, vt, attn);
    out_proj_kernel<<<dim3(64, 16), 256, 0, stream>>>(attn, WOt, out);
}